// Round 5
// baseline (6080.592 us; speedup 1.0000x reference)
//
#include <hip/hip_runtime.h>

// ---------------- types & helpers ----------------
typedef __bf16 bf16x8 __attribute__((ext_vector_type(8)));
typedef float  f32x4  __attribute__((ext_vector_type(4)));

__device__ __forceinline__ unsigned short f2bf(float f) {
    unsigned u = __float_as_uint(f);
    u += 0x7fffu + ((u >> 16) & 1u);   // RNE
    return (unsigned short)(u >> 16);
}

__device__ __forceinline__ void gld_lds16(const void* g, void* l) {
    __builtin_amdgcn_global_load_lds(
        (const __attribute__((address_space(1))) void*)g,
        (__attribute__((address_space(3))) void*)l,
        16, 0, 0);
}

#define WAITVM0()  asm volatile("s_waitcnt vmcnt(0)" ::: "memory")
#define WAITLGKM() asm volatile("s_waitcnt lgkmcnt(0)" ::: "memory")
#define SB0()      __builtin_amdgcn_sched_barrier(0)
#define BAR()      __builtin_amdgcn_s_barrier()

// ---------------- problem constants ----------------
#define NB  32
#define SQ  256
#define HD  1024
#define ID  4096
#define NEXP 8          // skill experts; index 8 = shared
#define PAIRS (NB * 3)  // (batch, slot) pairs

// workspace layout (bytes)
#define OFF_EID    ((size_t)0)            // 96 int
#define OFF_WGT    ((size_t)512)          // 96 float
#define OFF_XBF    ((size_t)1024)                       // 8192*1024 bf16
#define OFF_GATET  (OFF_XBF   + (size_t)16777216)       // 9*4096*1024 bf16
#define OFF_UPT    (OFF_GATET + (size_t)75497472)
#define OFF_DOWNT  (OFF_UPT   + (size_t)75497472)
#define OFF_ACT    (OFF_DOWNT + (size_t)75497472)       // 96*256*4096 bf16
// stage2 partials (fp32, 32 MB each) alias gateT/upT (dead after stage1)

// pair order sorted by expert id (locality for weight reuse)
__device__ int d_sord[PAIRS];

// ---------------- routing ----------------
__global__ void routing_kernel(const float* __restrict__ logits,
                               int* __restrict__ eid, float* __restrict__ wgt) {
    int b = threadIdx.x;
    if (b < NB) {
        float l[NEXP];
        for (int j = 0; j < NEXP; ++j) l[j] = logits[b * NEXP + j];
        int a0 = 0;
        for (int j = 1; j < NEXP; ++j) if (l[j] > l[a0]) a0 = j;
        int a1 = -1;
        for (int j = 0; j < NEXP; ++j) {
            if (j == a0) continue;
            if (a1 < 0 || l[j] > l[a1]) a1 = j;
        }
        float w0 = 1.0f / (1.0f + expf(l[a1] - l[a0]));
        eid[b * 3 + 0] = a0;  wgt[b * 3 + 0] = w0;
        eid[b * 3 + 1] = a1;  wgt[b * 3 + 1] = 1.0f - w0;
        eid[b * 3 + 2] = NEXP; wgt[b * 3 + 2] = 1.0f;   // shared
    }
    __syncthreads();
    if (threadIdx.x == 0) {
        int cnt[NEXP + 2];
        for (int i = 0; i < NEXP + 2; ++i) cnt[i] = 0;
        for (int i = 0; i < PAIRS; ++i) cnt[eid[i] + 1]++;
        for (int e = 0; e < NEXP + 1; ++e) cnt[e + 1] += cnt[e];
        for (int i = 0; i < PAIRS; ++i) d_sord[cnt[eid[i]]++] = i;
    }
}

// ---------------- x fp32 -> bf16 ----------------
__global__ void xcvt_kernel(const float* __restrict__ x,
                            unsigned short* __restrict__ xb, int n4) {
    int i = blockIdx.x * 256 + threadIdx.x;
    if (i < n4) {
        float4 v = ((const float4*)x)[i];
        union { unsigned short s[4]; uint2 u; } p;
        p.s[0] = f2bf(v.x); p.s[1] = f2bf(v.y);
        p.s[2] = f2bf(v.z); p.s[3] = f2bf(v.w);
        ((uint2*)xb)[i] = p.u;
    }
}

// ---------------- weight transpose+convert: [R][C] fp32 -> [C][R] bf16 ----------------
__global__ void transpose_cvt(const float* __restrict__ skill,
                              const float* __restrict__ shared_m,
                              unsigned short* __restrict__ out, int R, int C) {
    const int e = blockIdx.z;                       // 0..8
    const float* src = (e < NEXP) ? (skill + (size_t)e * R * C) : shared_m;
    unsigned short* dst = out + (size_t)e * R * C;  // [C][R]
    const int c0 = blockIdx.x * 64;
    const int r0 = blockIdx.y * 64;
    __shared__ unsigned short t[64][66];
    const int tid = threadIdx.x;
    const int lr = tid >> 4;            // 0..15
    const int lc = (tid & 15) * 4;
    for (int it = 0; it < 4; ++it) {
        int r = lr + it * 16;
        float4 v = *(const float4*)(src + (size_t)(r0 + r) * C + c0 + lc);
        t[r][lc + 0] = f2bf(v.x);
        t[r][lc + 1] = f2bf(v.y);
        t[r][lc + 2] = f2bf(v.z);
        t[r][lc + 3] = f2bf(v.w);
    }
    __syncthreads();
    const int oc = tid >> 2;            // out row (original col), 0..63
    const int k0 = (tid & 3) * 16;      // 16 elems along original rows
    unsigned int pk[8];
    for (int j = 0; j < 8; ++j) {
        unsigned int lo = t[k0 + 2 * j + 0][oc];
        unsigned int hi = t[k0 + 2 * j + 1][oc];
        pk[j] = lo | (hi << 16);
    }
    unsigned short* dp = dst + (size_t)(c0 + oc) * R + r0 + k0;
    ((uint4*)dp)[0] = make_uint4(pk[0], pk[1], pk[2], pk[3]);
    ((uint4*)dp)[1] = make_uint4(pk[4], pk[5], pk[6], pk[7]);
}

// =====================================================================
// stage1: act = gelu(x@gate) * (x@up) * w  (bf16 out)
// BM=256 x BN=128 I x {G,U}, BK=32; 8 waves (2M x 4N), wave 128x64.
// LDS 64 KiB (2 buf x [A 256x32 | B 256x32]) -> 2 blocks/CU (TLP).
// Simple per-tile schedule; cross-block overlap fills sync bubbles.
// =====================================================================
__global__ __launch_bounds__(512, 4) void stage1_gateup(
    const unsigned short* __restrict__ xbf,     // [8192][1024]
    const unsigned short* __restrict__ gateT,   // [9][4096][1024]
    const unsigned short* __restrict__ upT,
    const int* __restrict__ eid, const float* __restrict__ wgt,
    unsigned short* __restrict__ act)           // [96][256][4096]
{
    extern __shared__ unsigned short lds[];     // 2 x 16384 shorts = 64 KiB

    // locality: XCD g owns 12 sorted pairs; subgroups of 4 pairs, nt outer
    const int bid = blockIdx.x;                 // 0..3071
    const int g   = bid & 7;
    const int r0_ = bid >> 3;                   // 0..383
    const int sg  = r0_ >> 7;                   // 0..2
    const int rr  = r0_ & 127;
    const int nt  = rr >> 2;                    // 0..31 (I tile of 128)
    const int pi  = rr & 3;
    const int p   = d_sord[g * 12 + sg * 4 + pi];
    const int b   = p / 3;
    const int e   = eid[p];
    const float wS = wgt[p];

    const int tid  = threadIdx.x;
    const int wv   = tid >> 6;
    const int lane = tid & 63;
    const int wr   = wv >> 2;          // 0..1 : M half (128 rows)
    const int wc   = wv & 3;           // 0..3 : 32-I-col slice
    const int lrow = lane & 15;
    const int chunk = lane >> 4;       // 0..3
    const int lr4  = lane >> 2;

    // staging: lane l -> LDS row l>>2 (within 16-row seg), chunk l&3;
    // source chunk pre-swizzled = (l&3)^((l>>3)&3)
    const int stc8 = (((lane & 3) ^ ((lane >> 3) & 3)) << 3);
    const int dA   = wv * 1024;        // shorts; q adds 512

    const unsigned short* pa[2];
    const unsigned short* pb[2];
#pragma unroll
    for (int q = 0; q < 2; ++q) {
        const int seg = wv * 2 + q;    // 16-row segment 0..15
        pa[q] = xbf + ((size_t)(b * SQ + seg * 16 + lr4)) * HD + stc8;
        const int s    = (seg >> 1) & 1;                       // 0=G 1=U
        const int icol = nt * 128 + (seg >> 2) * 32 + (seg & 1) * 16 + lr4;
        pb[q] = (s ? upT : gateT) + ((size_t)e * ID + icol) * HD + stc8;
    }

    // frag-read offsets (shorts); read swizzle: chunk ^ ((row>>1)&3)
    const int csw = ((chunk ^ ((lrow >> 1) & 3)) << 3);
    const int rdA = (wr * 128 + lrow) * 32 + csw;
    const int rdB = 8192 + (wc * 64 + lrow) * 32 + csw;

    f32x4 acc[8][4];
#pragma unroll
    for (int i = 0; i < 8; ++i)
#pragma unroll
        for (int j = 0; j < 4; ++j) acc[i][j] = (f32x4)0.f;

    // prologue: stage tile 0 -> buf 0
    gld_lds16(pa[0], lds + dA);
    gld_lds16(pa[1], lds + dA + 512);
    gld_lds16(pb[0], lds + 8192 + dA);
    gld_lds16(pb[1], lds + 8192 + dA + 512);
    SB0(); WAITVM0(); SB0();
    BAR();
    SB0();

    const int NT = HD / 32;   // 32 K-tiles
#pragma unroll 1
    for (int t = 0; t < NT; ++t) {
        unsigned short* Lc = lds + (t & 1) * 16384;
        unsigned short* Ln = lds + ((t & 1) ^ 1) * 16384;
        const bool pf = (t + 1 < NT);
        const int kof = (t + 1) * 32;

        if (pf) {
            gld_lds16(pa[0] + kof, Ln + dA);
            gld_lds16(pa[1] + kof, Ln + dA + 512);
            gld_lds16(pb[0] + kof, Ln + 8192 + dA);
            gld_lds16(pb[1] + kof, Ln + 8192 + dA + 512);
        }

        bf16x8 av0[4], av1[4], bv[4];
#pragma unroll
        for (int i = 0; i < 4; ++i) {
            av0[i] = *(const bf16x8*)(Lc + rdA + i * 512);
            av1[i] = *(const bf16x8*)(Lc + rdA + (4 + i) * 512);
            bv[i]  = *(const bf16x8*)(Lc + rdB + i * 512);
        }

        __builtin_amdgcn_s_setprio(1);
#pragma unroll
        for (int mi = 0; mi < 4; ++mi)
#pragma unroll
            for (int ni = 0; ni < 4; ++ni)
                acc[mi][ni] = __builtin_amdgcn_mfma_f32_16x16x32_bf16(av0[mi], bv[ni], acc[mi][ni], 0, 0, 0);
#pragma unroll
        for (int mi = 0; mi < 4; ++mi)
#pragma unroll
            for (int ni = 0; ni < 4; ++ni)
                acc[4 + mi][ni] = __builtin_amdgcn_mfma_f32_16x16x32_bf16(av1[mi], bv[ni], acc[4 + mi][ni], 0, 0, 0);
        __builtin_amdgcn_s_setprio(0);

        // own LDS reads of Lc done + own stages of Ln done -> barrier
        WAITLGKM();
        WAITVM0();
        SB0();
        BAR();
        SB0();
    }

    // epilogue: gelu(g)*u*w -> bf16 (acc[.][0,1]=G, acc[.][2,3]=U)
    unsigned short* actp = act + (size_t)p * (SQ * ID);
    const int rb = wr * 128 + (chunk << 2);
    const int cb = nt * 128 + wc * 32 + lrow;
#pragma unroll
    for (int mf = 0; mf < 8; ++mf)
#pragma unroll
        for (int pp = 0; pp < 2; ++pp)
#pragma unroll
            for (int r2 = 0; r2 < 4; ++r2) {
                float gv = acc[mf][pp][r2];
                float uv = acc[mf][pp + 2][r2];
                float t2 = -1.5957691216057308f * gv * (1.0f + 0.044715f * gv * gv);
                float h  = __fdividef(gv, 1.0f + __expf(t2)) * uv * wS;
                actp[(size_t)(rb + mf * 16 + r2) * ID + cb + pp * 16] = f2bf(h);
            }
}

// =====================================================================
// stage2: out_slot = act[p] @ downT[e(p)]  (fp32, per-slot partials)
// BM=128, BN=256, BK=32, K=4096 (single expert panel per block).
// Grid = 96 pairs x 2 mt x 4 ntH = 768 = exactly 3 blocks/CU.
// LDS 48 KiB (2 buf x [A 128x32 | B 256x32]) -> 3 blocks/CU (TLP).
// Expert-sorted XCD mapping: same-expert pairs share B panels in L2.
// =====================================================================
__global__ __launch_bounds__(512, 6) void stage2_down(
    const unsigned short* __restrict__ act,     // [96][256][4096]
    const unsigned short* __restrict__ downT,   // [9][1024][4096]
    const int* __restrict__ eid,
    float* __restrict__ out,                    // slot 0
    float* __restrict__ p1,                     // slot 1
    float* __restrict__ p2)                     // slot 2
{
    extern __shared__ unsigned short lds[];     // 2 x 12288 shorts = 48 KiB

    // XCD g owns 12 sorted pairs -> 96 blocks; subgroups of 4 pairs;
    // ntH outer, (pair, mt) inner.
    const int bid = blockIdx.x;                 // 0..767
    const int g   = bid & 7;
    const int r   = bid >> 3;                   // 0..95
    const int sg  = r >> 5;                     // 0..2
    const int rr  = r & 31;
    const int ntH = rr >> 3;                    // 0..3
    const int q   = rr & 7;
    const int j   = g * 12 + sg * 4 + (q >> 1);
    const int mt  = q & 1;
    const int p   = d_sord[j];
    const int b   = p / 3;
    const int slot = p - b * 3;
    const int e   = eid[p];

    const int tid  = threadIdx.x;
    const int wv   = tid >> 6;
    const int lane = tid & 63;
    const int wr   = wv >> 2;          // 0..1 : 64-row half
    const int wc   = wv & 3;           // 0..3 : 64-col slice
    const int lrow = lane & 15;
    const int chunk = lane >> 4;

    // staging: thread t -> row t>>2, chunk t&3 (A); rows +128 for B q1
    const int srow = tid >> 2;
    const int stc8 = (((tid & 3) ^ ((tid >> 3) & 3)) << 3);
    const unsigned short* pa  = act   + ((size_t)p * SQ + mt * 128 + srow) * ID + stc8;
    const unsigned short* pb0 = downT + ((size_t)e * HD + ntH * 256 + srow) * ID + stc8;
    const unsigned short* pb1 = pb0 + (size_t)128 * ID;
    const int dW = wv * 512;           // wave-uniform dest (shorts)

    const int csw = ((chunk ^ ((lrow >> 1) & 3)) << 3);
    const int rdA = (wr * 64 + lrow) * 32 + csw;
    const int rdB = 4096 + (wc * 64 + lrow) * 32 + csw;

    f32x4 acc[4][4];
#pragma unroll
    for (int i = 0; i < 4; ++i)
#pragma unroll
        for (int jj = 0; jj < 4; ++jj) acc[i][jj] = (f32x4)0.f;

    // prologue: tile 0 -> buf 0
    gld_lds16(pa,  lds + dW);
    gld_lds16(pb0, lds + 4096 + dW);
    gld_lds16(pb1, lds + 8192 + dW);
    SB0(); WAITVM0(); SB0();
    BAR();
    SB0();

    const int NT = ID / 32;   // 128 K-tiles
#pragma unroll 1
    for (int t = 0; t < NT; ++t) {
        unsigned short* Lc = lds + (t & 1) * 12288;
        unsigned short* Ln = lds + ((t & 1) ^ 1) * 12288;
        const bool pf = (t + 1 < NT);
        const int kof = (t + 1) * 32;

        if (pf) {
            gld_lds16(pa  + kof, Ln + dW);
            gld_lds16(pb0 + kof, Ln + 4096 + dW);
            gld_lds16(pb1 + kof, Ln + 8192 + dW);
        }

        bf16x8 av[4], bv[4];
#pragma unroll
        for (int i = 0; i < 4; ++i) {
            av[i] = *(const bf16x8*)(Lc + rdA + i * 512);
            bv[i] = *(const bf16x8*)(Lc + rdB + i * 512);
        }

        __builtin_amdgcn_s_setprio(1);
#pragma unroll
        for (int mi = 0; mi < 4; ++mi)
#pragma unroll
            for (int ni = 0; ni < 4; ++ni)
                acc[mi][ni] = __builtin_amdgcn_mfma_f32_16x16x32_bf16(av[mi], bv[ni], acc[mi][ni], 0, 0, 0);
        __builtin_amdgcn_s_setprio(0);

        WAITLGKM();
        WAITVM0();
        SB0();
        BAR();
        SB0();
    }

    float* dst = (slot == 0) ? out : ((slot == 1) ? p1 : p2);
    const int rb = mt * 128 + wr * 64 + (chunk << 2);
    const int cb = ntH * 256 + wc * 64 + lrow;
#pragma unroll
    for (int mf = 0; mf < 4; ++mf)
#pragma unroll
        for (int nf = 0; nf < 4; ++nf)
#pragma unroll
            for (int r2 = 0; r2 < 4; ++r2)
                dst[((size_t)b * SQ + rb + mf * 16 + r2) * HD + cb + nf * 16] = acc[mf][nf][r2];
}

// ---------------- combine: out += p1 + p2 ----------------
__global__ void combine_kernel(float* __restrict__ out,
                               const float* __restrict__ p1,
                               const float* __restrict__ p2, int n4) {
    int i = blockIdx.x * 256 + threadIdx.x;
    if (i < n4) {
        float4 a = ((const float4*)out)[i];
        float4 c = ((const float4*)p1)[i];
        float4 d = ((const float4*)p2)[i];
        a.x += c.x + d.x; a.y += c.y + d.y;
        a.z += c.z + d.z; a.w += c.w + d.w;
        ((float4*)out)[i] = a;
    }
}

// ---------------- host ----------------
extern "C" void kernel_launch(void* const* d_in, const int* in_sizes, int n_in,
                              void* d_out, int out_size, void* d_ws, size_t ws_size,
                              hipStream_t stream) {
    const float* x        = (const float*)d_in[0];
    const float* logits   = (const float*)d_in[1];
    const float* sk_gate  = (const float*)d_in[2];
    const float* sk_up    = (const float*)d_in[3];
    const float* sk_down  = (const float*)d_in[4];
    const float* sh_gate  = (const float*)d_in[5];
    const float* sh_up    = (const float*)d_in[6];
    const float* sh_down  = (const float*)d_in[7];
    float* out = (float*)d_out;

    char* ws = (char*)d_ws;
    int*            eid   = (int*)(ws + OFF_EID);
    float*          wgt   = (float*)(ws + OFF_WGT);
    unsigned short* xbf   = (unsigned short*)(ws + OFF_XBF);
    unsigned short* gateT = (unsigned short*)(ws + OFF_GATET);
    unsigned short* upT   = (unsigned short*)(ws + OFF_UPT);
    unsigned short* downT = (unsigned short*)(ws + OFF_DOWNT);
    unsigned short* act   = (unsigned short*)(ws + OFF_ACT);
    float*          part1 = (float*)(ws + OFF_GATET);   // reuse dead gateT
    float*          part2 = (float*)(ws + OFF_UPT);     // reuse dead upT

    static int attr_set = 0;
    if (!attr_set) {
        hipFuncSetAttribute(reinterpret_cast<const void*>(stage1_gateup),
                            hipFuncAttributeMaxDynamicSharedMemorySize, 65536);
        hipFuncSetAttribute(reinterpret_cast<const void*>(stage2_down),
                            hipFuncAttributeMaxDynamicSharedMemorySize, 49152);
        attr_set = 1;
    }

    routing_kernel<<<1, 64, 0, stream>>>(logits, eid, wgt);

    const int n4 = (NB * SQ * HD) / 4;
    xcvt_kernel<<<(n4 + 255) / 256, 256, 0, stream>>>(x, xbf, n4);

    transpose_cvt<<<dim3(ID / 64, HD / 64, 9), 256, 0, stream>>>(sk_gate, sh_gate, gateT, HD, ID);
    transpose_cvt<<<dim3(ID / 64, HD / 64, 9), 256, 0, stream>>>(sk_up,   sh_up,   upT,   HD, ID);
    transpose_cvt<<<dim3(HD / 64, ID / 64, 9), 256, 0, stream>>>(sk_down, sh_down, downT, ID, HD);

    stage1_gateup<<<dim3(PAIRS * 32), 512, 65536, stream>>>(xbf, gateT, upT, eid, wgt, act);
    stage2_down<<<dim3(768), 512, 49152, stream>>>(act, downT, eid, out, part1, part2);

    const int c4 = (NB * SQ * HD) / 4;
    combine_kernel<<<(c4 + 255) / 256, 256, 0, stream>>>(out, part1, part2, c4);
}